// Round 2
// baseline (4401.286 us; speedup 1.0000x reference)
//
#include <hip/hip_runtime.h>
#include <cstdint>
#include <cstddef>

// =====================================================================
// RBM Gibbs sampling, bit-exact replication of JAX-on-CPU reference.
// ROUND 12 (perf): two structural changes.
// (1) k_sample_v split into k_gemm_v (dense h-major fma, Nb=16 b's per
//     thread, bit-floats precomputed once into LDS tbf[256][16] and
//     read via broadcast ds_read_b128 -- removes the per-(h,i) bfe+cvt
//     redundancy and the 40-reg best/bc live range that made R11
//     VALU-issue-bound at 2.3x the instr floor) + k_gumbel_v (RNG +
//     argmax, verbatim R11 epilogue expressions). Sums staged in the
//     out_v region of d_out (167MB >= 160MB; only k_onehot writes it,
//     last) -- no ws growth.
// (2) k_sample_h: 16 b per block x 128-h half, Wt staged to LDS in
//     16-row double-buffered chunks; per-b sorted k-lists (u16) walk
//     each chunk. L2 traffic 8.4GB -> 2.7GB per dispatch. psum resets
//     at k%320==0 (chunk%20==0, aligned), sequential fold preserved.
// Bit-exactness: gemm = same h-ascending fma chain, f in {0,1} exact,
// acc never -0.0; sums f32 round-trip exact; gumbel = R11 expressions
// and RNG indices unchanged; sample_h = same k-ascending chain + same
// slab folds (empty slab-8 fold was +0.0 identity).
// Semantics FROZEN (rounds 6-11 passed, absmax=0):
//  - threefry2x32 partitionable; fold-like split; seed(42)->(0,42).
//  - cephes-Horner exp, Pommier-Horner log (q1/q2 tail), no contract.
//  - sigmoid = 1/(1+exp(-x)) IEEE div; gumbel tiny-clamp; first-max
//    argmax; bernoulli u<p; v-GEMM K=256 single sequential chain.
//  - h-GEMM: Eigen gebp kc=320 slab fold, k ascending (c-major).
// ws layout unchanged; sentinel reads back ws_size as absmax if short.
// =====================================================================

#define B_DIM 16384
#define C_DIM 5
#define H_DIM 256
#define V_DIM 512

struct TFOut { uint32_t a, b; };

__host__ __device__ static inline TFOut tf2x32(uint32_t k0, uint32_t k1,
                                               uint32_t c0, uint32_t c1) {
  uint32_t ks2 = k0 ^ k1 ^ 0x1BD11BDAu;
  uint32_t x0 = c0 + k0, x1 = c1 + k1;
#define TF_R(r) { x0 += x1; x1 = (x1 << r) | (x1 >> (32 - r)); x1 ^= x0; }
  TF_R(13) TF_R(15) TF_R(26) TF_R(6)
  x0 += k1;  x1 += ks2 + 1u;
  TF_R(17) TF_R(29) TF_R(16) TF_R(24)
  x0 += ks2; x1 += k0 + 2u;
  TF_R(13) TF_R(15) TF_R(26) TF_R(6)
  x0 += k0;  x1 += k1 + 3u;
  TF_R(17) TF_R(29) TF_R(16) TF_R(24)
  x0 += k1;  x1 += ks2 + 4u;
  TF_R(13) TF_R(15) TF_R(26) TF_R(6)
  x0 += ks2; x1 += k0 + 5u;
#undef TF_R
  TFOut o; o.a = x0; o.b = x1; return o;
}

// partitionable random_bits, 32-bit width, element index i (< 2^32)
__device__ static inline uint32_t rng_bits(uint32_t k0, uint32_t k1, uint32_t i) {
  TFOut r = tf2x32(k0, k1, 0u, i);
  return r.a ^ r.b;
}

__device__ static inline float bits_to_unit_float(uint32_t bits) {
  return __uint_as_float((bits >> 9) | 0x3F800000u) - 1.0f;
}

// XLA GenerateVF32Exp replica (cephes Horner port), mul+add separate,
// NO contraction.
__device__ static float xla_exp(float x_in) {
#pragma clang fp contract(off)
  float x = fminf(x_in, 88.3762626647950f);
  x = fmaxf(x, -88.3762626647949f);
  float fx = floorf(x * 1.44269504088896341f + 0.5f);
  float tmp = fx * 0.693359375f;
  float z = fx * -2.12194440e-4f;
  x = x - tmp;
  x = x - z;
  z = x * x;
  float y = 1.9875691500e-4f;
  y = y * x + 1.3981999507e-3f;
  y = y * x + 8.3334519073e-3f;
  y = y * x + 4.1665795894e-2f;
  y = y * x + 1.6666665459e-1f;
  y = y * x + 5.0000001201e-1f;
  y = y * z + x;
  y = y + 1.0f;
  int n = (int)fx;
  y = y * __uint_as_float((uint32_t)(n + 127) << 23);
  return y;
}

// XLA GenerateVF32Log replica = Pommier/Eigen3.3 log_ps (Horner + tail:
// y+=e*q1; y-=0.5*z; x+=y; x+=e*q2). NO contraction.
__device__ static float xla_log(float x_in) {
#pragma clang fp contract(off)
  float xv = fmaxf(x_in, 1.17549435e-38f);      // min_norm_pos clamp
  uint32_t bits = __float_as_uint(xv);
  float e = (float)((int)(bits >> 23) - 126);
  float x = __uint_as_float((bits & 0x007FFFFFu) | 0x3F000000u);  // [0.5,1)
  bool m = (x < 0.707106781186547524f);
  float tmp = m ? x : 0.0f;
  x = x - 1.0f;
  e = e - (m ? 1.0f : 0.0f);
  x = x + tmp;
  float z = x * x;
  float y = 7.0376836292e-2f;
  y = y * x + -1.1514610310e-1f;
  y = y * x + 1.1676998740e-1f;
  y = y * x + -1.2420140846e-1f;
  y = y * x + 1.4249322787e-1f;
  y = y * x + -1.6668057665e-1f;
  y = y * x + 2.0000714765e-1f;
  y = y * x + -2.4999993993e-1f;
  y = y * x + 3.3333331174e-1f;
  y = y * x;
  y = y * z;
  float t1 = e * -2.12194440e-4f;
  y = y + t1;
  float t2 = z * 0.5f;
  y = y - t2;
  x = x + y;
  float t3 = e * 0.693359375f;
  x = x + t3;
  return x;
}

// ---------------- kernels ----------------

__global__ void k_sentinel(float* out, float d) {
  out[0] = d;
}

// v0 one-hot (B,C,V) -> idx (B,V) u8
__global__ __launch_bounds__(256) void k_idx(const float* __restrict__ v0,
                                             uint8_t* __restrict__ idx) {
  int t = blockIdx.x * 256 + threadIdx.x;          // b*V + v
  int b = t >> 9, v = t & 511;
  const float* p = v0 + (size_t)b * (C_DIM * V_DIM) + v;
  int cf = 0;
#pragma unroll
  for (int c = 0; c < C_DIM; ++c)
    if (p[c * V_DIM] > 0.5f) cf = c;
  idx[t] = (uint8_t)cf;
}

// W (c,h,v) -> Wt (c,v,h)
__global__ __launch_bounds__(256) void k_wt(const float* __restrict__ W,
                                            float* __restrict__ Wt) {
  int t = blockIdx.x * 256 + threadIdx.x;          // (c, v, h)
  int h = t & 255; int rest = t >> 8; int v = rest & 511; int c = rest >> 9;
  Wt[t] = W[((size_t)c * H_DIM + h) * V_DIM + v];
}

// =====================================================================
// k_sample_h: h = bernoulli(sigmoid(kc-slab-folded k-ascending sum + c1))
// Block = 16 b x 128-h half. Wt staged into LDS in 16-row dbuf chunks;
// per-b sorted k-lists (u16) walk each chunk. Chain per (b,h): selected
// k ascending, psum reset at k%320==0, sequential fold -- identical to
// the R7-R11 jb/KC structure.
// =====================================================================
__global__ __launch_bounds__(256, 4) void k_sample_h(
    const float* __restrict__ Wt, const float* __restrict__ c1g,
    const uint8_t* __restrict__ idx,
    float* __restrict__ out_h, uint32_t* __restrict__ out_mask,
    uint32_t key0, uint32_t key1) {
  __shared__ uint8_t  sidx[V_DIM];
  __shared__ uint16_t soff[16][V_DIM];          // per-b selected k asc
  __shared__ __align__(16) float slab[2][16 * 128];  // dbuf 16 rows x h-half
  __shared__ uint16_t cnt[8][5];
  __shared__ uint16_t base[8][5];
  __shared__ uint32_t hb32[16][4];

  int t = threadIdx.x;
  int bb = blockIdx.x >> 1, hh = blockIdx.x & 1;
  int b0 = bb * 16, h0 = hh * 128;
  int wv = t >> 6, lane = t & 63;

  // ---- phase A: per-b compaction (16x the R7 scheme, k as u16) ----
  for (int bi = 0; bi < 16; ++bi) {
    if (t < 128)
      ((uint32_t*)sidx)[t] =
          ((const uint32_t*)(idx + (size_t)(b0 + bi) * V_DIM))[t];
    __syncthreads();
    int v0 = t, c0 = sidx[v0];
    int v1 = t + 256, c1i = sidx[v1];
    int rank0, rank1;
    {
      unsigned long long bal[5];
#pragma unroll
      for (int cc = 0; cc < 5; ++cc) bal[cc] = __ballot(c0 == cc);
      if (lane == 0) {
#pragma unroll
        for (int cc = 0; cc < 5; ++cc) cnt[wv][cc] = (uint16_t)__popcll(bal[cc]);
      }
      rank0 = (int)__popcll(bal[c0] & ((1ull << lane) - 1ull));
    }
    {
      unsigned long long bal[5];
#pragma unroll
      for (int cc = 0; cc < 5; ++cc) bal[cc] = __ballot(c1i == cc);
      if (lane == 0) {
#pragma unroll
        for (int cc = 0; cc < 5; ++cc) cnt[4 + wv][cc] = (uint16_t)__popcll(bal[cc]);
      }
      rank1 = (int)__popcll(bal[c1i] & ((1ull << lane) - 1ull));
    }
    __syncthreads();
    if (t == 0) {
      int pos = 0;
      for (int cc = 0; cc < 5; ++cc)
        for (int gg = 0; gg < 8; ++gg) { base[gg][cc] = (uint16_t)pos; pos += cnt[gg][cc]; }
    }
    __syncthreads();
    soff[bi][base[wv][c0] + rank0]      = (uint16_t)(c0 * V_DIM + v0);
    soff[bi][base[4 + wv][c1i] + rank1] = (uint16_t)(c1i * V_DIM + v1);
    __syncthreads();
  }

  // ---- phase B: chunked accumulate; wave g owns b's g*4..g*4+3 ----
  float ps0[4], ps1[4], tt0[4], tt1[4];
  int jp[4];
#pragma unroll
  for (int i = 0; i < 4; ++i) {
    ps0[i] = 0.f; ps1[i] = 0.f; tt0[i] = 0.f; tt1[i] = 0.f; jp[i] = 0;
  }

  // prologue: stage chunk 0
  {
    int p = t * 4;
    int row = p >> 7, off = p & 127;
    const float* s = Wt + (size_t)row * H_DIM + h0 + off;
    float4 r0 = *(const float4*)s;
    float4 r1 = *(const float4*)(s + 8 * H_DIM);
    *(float4*)&slab[0][row * 128 + off] = r0;
    *(float4*)&slab[0][(row + 8) * 128 + off] = r1;
  }
  __syncthreads();

  for (int ch = 0; ch < 160; ++ch) {
    int buf = ch & 1;
    float4 r0, r1; int row = 0, off = 0;
    bool pre = (ch + 1 < 160);
    if (pre) {   // issue next-chunk loads early (hide under compute)
      int p = t * 4;
      row = p >> 7; off = p & 127;
      const float* s = Wt + ((size_t)(ch + 1) * 16 + row) * H_DIM + h0 + off;
      r0 = *(const float4*)s;
      r1 = *(const float4*)(s + 8 * H_DIM);
    }
    if ((ch % 20) == 0) {     // slab boundary k%320==0 (identity at ch=0)
#pragma unroll
      for (int i = 0; i < 4; ++i) {
        tt0[i] = tt0[i] + ps0[i]; ps0[i] = 0.f;
        tt1[i] = tt1[i] + ps1[i]; ps1[i] = 0.f;
      }
    }
    int kend = ch * 16 + 16;
#pragma unroll
    for (int i = 0; i < 4; ++i) {
      int bi = wv * 4 + i;
      int j = jp[i];
      float p0 = ps0[i], p1 = ps1[i];
      while (j < 512) {
        int k = soff[bi][j];
        if (k >= kend) break;
        const float* wp = &slab[buf][(k & 15) * 128 + (lane << 1)];
        float2 w2 = *(const float2*)wp;
        p0 += w2.x;
        p1 += w2.y;
        ++j;
      }
      ps0[i] = p0; ps1[i] = p1; jp[i] = j;
    }
    __syncthreads();          // all reads of buf^1 (at ch-1) done
    if (pre) {
      *(float4*)&slab[buf ^ 1][row * 128 + off] = r0;
      *(float4*)&slab[buf ^ 1][(row + 8) * 128 + off] = r1;
    }
    __syncthreads();          // next chunk visible
  }
#pragma unroll
  for (int i = 0; i < 4; ++i) {   // final slab fold
    tt0[i] = tt0[i] + ps0[i];
    tt1[i] = tt1[i] + ps1[i];
  }

  // ---- epilogue: sigmoid + bernoulli + mask ----
  if (t < 64) ((uint32_t*)hb32)[t] = 0u;
  __syncthreads();
  float2 c1v = *(const float2*)&c1g[h0 + (lane << 1)];
  int h = h0 + (lane << 1);
#pragma unroll
  for (int i = 0; i < 4; ++i) {
    int b = b0 + wv * 4 + i;
    float ta = tt0[i] + c1v.x;
    float tb = tt1[i] + c1v.y;
    float pa = 1.0f / (1.0f + xla_exp(-ta));   // IEEE div, logistic exp form
    float pb = 1.0f / (1.0f + xla_exp(-tb));
    float ua = bits_to_unit_float(rng_bits(key0, key1, (uint32_t)(b * H_DIM + h)));
    float ub = bits_to_unit_float(rng_bits(key0, key1, (uint32_t)(b * H_DIM + h + 1)));
    bool ha = ua < pa, hb = ub < pb;
    if (out_h) {
      float2 o; o.x = ha ? 1.0f : 0.0f; o.y = hb ? 1.0f : 0.0f;
      *(float2*)&out_h[(size_t)b * H_DIM + h] = o;
    }
    uint32_t bitpos = (uint32_t)((lane << 1) & 31);
    uint32_t val = ((ha ? 1u : 0u) << bitpos) | ((hb ? 1u : 0u) << (bitpos + 1));
    atomicOr(&hb32[wv * 4 + i][lane >> 4], val);
  }
  __syncthreads();
  if (t < 64) {
    int bl = t >> 2, wl = t & 3;
    out_mask[(size_t)(b0 + bl) * 8 + hh * 4 + wl] = hb32[bl][wl];
  }
}

// =====================================================================
// k_gemm_v: sums[c][b][v] = h-ascending dense fma chain (f in {0,1}).
// Block = 16 b x 512 v; 4 waves = 4 v-quarters; thread = 16 b x 2 v.
// Bit-floats precomputed once into tbf[256][16]; per h: 1 float2 W load
// + 4 broadcast ds_read_b128 + 32 fma. Same chain as R11 (bit-exact).
// =====================================================================
#define GEMM_PAIR(i, F)                      \
  a0[i] = fmaf(w2.x, F, a0[i]);              \
  a1[i] = fmaf(w2.y, F, a1[i]);

__global__ __launch_bounds__(256, 4) void k_gemm_v(
    const float* __restrict__ W, const uint32_t* __restrict__ mask,
    float* __restrict__ sums) {
  __shared__ uint32_t smask[16][8];
  __shared__ __align__(16) float tbf[H_DIM][16];
  int t = threadIdx.x;
  int b0 = blockIdx.x * 16;
  if (t < 128) smask[t >> 3][t & 7] = mask[(size_t)b0 * 8 + t];
  __syncthreads();
  {
    int h = t;
    uint32_t w = (uint32_t)(h >> 5), s = (uint32_t)(h & 31), x = 0;
#pragma unroll
    for (int j = 0; j < 16; ++j)
      x |= ((smask[j][w] >> s) & 1u) << j;
#pragma unroll
    for (int i = 0; i < 16; ++i)
      tbf[h][i] = (float)((x >> i) & 1u);
  }
  __syncthreads();

  int wv = t >> 6, lane = t & 63;
  int v0 = wv * 128 + (lane << 1);

  for (int c = 0; c < C_DIM; ++c) {
    float a0[16], a1[16];
#pragma unroll
    for (int i = 0; i < 16; ++i) { a0[i] = 0.f; a1[i] = 0.f; }
    const float* wp = W + (size_t)c * (H_DIM * V_DIM) + v0;
#pragma unroll 2
    for (int h = 0; h < H_DIM; ++h) {
      float2 w2 = *(const float2*)wp;
      wp += V_DIM;
      const float4* fp = (const float4*)&tbf[h][0];
      float4 fA = fp[0], fB = fp[1], fC = fp[2], fD = fp[3];
      GEMM_PAIR(0,  fA.x) GEMM_PAIR(1,  fA.y) GEMM_PAIR(2,  fA.z) GEMM_PAIR(3,  fA.w)
      GEMM_PAIR(4,  fB.x) GEMM_PAIR(5,  fB.y) GEMM_PAIR(6,  fB.z) GEMM_PAIR(7,  fB.w)
      GEMM_PAIR(8,  fC.x) GEMM_PAIR(9,  fC.y) GEMM_PAIR(10, fC.z) GEMM_PAIR(11, fC.w)
      GEMM_PAIR(12, fD.x) GEMM_PAIR(13, fD.y) GEMM_PAIR(14, fD.z) GEMM_PAIR(15, fD.w)
    }
#pragma unroll
    for (int i = 0; i < 16; ++i) {
      float2 o; o.x = a0[i]; o.y = a1[i];
      *(float2*)&sums[((size_t)c * B_DIM + b0 + i) * V_DIM + v0] = o;
    }
  }
}

// =====================================================================
// k_gumbel_v: v = categorical over c (gumbel + first-max argmax),
// reading the staged sums. Expressions/RNG identical to R11 epilogue.
// =====================================================================
__global__ __launch_bounds__(256, 4) void k_gumbel_v(
    const float* __restrict__ sums, const float* __restrict__ b2,
    uint8_t* __restrict__ idx_out, uint32_t key0, uint32_t key1) {
  int gidx = blockIdx.x * 256 + threadIdx.x;
  int b = gidx >> 7;
  int v0 = (gidx & 127) << 2;
  float best[4];
  uint32_t bc = 0;
#pragma unroll
  for (int c = 0; c < C_DIM; ++c) {
    float4 av = *(const float4*)&sums[((size_t)c * B_DIM + b) * V_DIM + v0];
    float4 bv = *(const float4*)&b2[c * V_DIM + v0];
    uint32_t ib = ((uint32_t)b * C_DIM + (uint32_t)c) * V_DIM + (uint32_t)v0;
    float avq[4] = {av.x, av.y, av.z, av.w};
    float bvq[4] = {bv.x, bv.y, bv.z, bv.w};
#pragma unroll
    for (int q = 0; q < 4; ++q) {
      float uf = bits_to_unit_float(rng_bits(key0, key1, ib + (uint32_t)q));
      if (uf == 0.0f) uf = 1.17549435e-38f;        // u + tiny semantics
      float gz = -xla_log(-xla_log(uf));
      float z = gz + (avq[q] + bvq[q]);
      if (c == 0 || z > best[q]) {
        best[q] = z;
        bc = (bc & ~(0xFFu << (8 * q))) | ((uint32_t)c << (8 * q));
      }
    }
  }
  *(uint32_t*)(idx_out + (size_t)b * V_DIM + v0) = bc;
}

// idx -> one-hot f32 (B,C,V)
__global__ __launch_bounds__(256) void k_onehot(const uint8_t* __restrict__ idx,
                                                float* __restrict__ out) {
  int t = blockIdx.x * 256 + threadIdx.x;     // b*C*V + c*V + v
  int v = t & 511; int rest = t >> 9; int c = rest % C_DIM; int b = rest / C_DIM;
  out[t] = (idx[(size_t)b * V_DIM + v] == c) ? 1.0f : 0.0f;
}

// ---------------- launch ----------------

extern "C" void kernel_launch(void* const* d_in, const int* in_sizes, int n_in,
                              void* d_out, int out_size, void* d_ws, size_t ws_size,
                              hipStream_t stream) {
  float* out = (float*)d_out;

  // ---- structural sentinels ----
  const size_t WS_NEED = 2621440ull      // Wt
                       + 2621440ull      // (reserved, layout kept)
                       + 8388608ull      // idx
                       + 524288ull;      // mask  = 14,155,776 B
  float D = 0.0f;
  if (n_in < 4)                       D = 910.0f + (float)n_in;
  else if (in_sizes[0] != 41943040)   D = 920.0f;
  else if (in_sizes[1] != 655360)     D = 921.0f;
  else if (in_sizes[2] != 2560)       D = 922.0f;
  else if (in_sizes[3] != 256)        D = 923.0f;
  else if (out_size != 50331648)      D = 930.0f + (float)out_size * 1e-6f;
  else if (ws_size < WS_NEED)         D = 100.0f + (float)(ws_size >> 20);
  if (D != 0.0f) {
    hipLaunchKernelGGL(k_sentinel, dim3(1), dim3(1), 0, stream, out, D);
    return;
  }

  const float* v0 = (const float*)d_in[0];
  const float* W  = (const float*)d_in[1];
  const float* b2 = (const float*)d_in[2];   // (C,V)
  const float* c1 = (const float*)d_in[3];   // (H)

  float* out_v  = out;                                         // B*C*V
  float* out_h  = out + (size_t)B_DIM * C_DIM * V_DIM;         // B*H (final h)
  float* out_h0 = out_h + (size_t)B_DIM * H_DIM;               // B*H (h|v0)

  char* ws = (char*)d_ws;
  float*    Wt   = (float*)(ws);                    // 2,621,440 B
  uint8_t*  idx  = (uint8_t*)(ws + 5242880);        // 8,388,608 B
  uint32_t* mask = (uint32_t*)(ws + 13631488);      //   524,288 B

  // sums scratch lives in the out_v region (167MB >= 160MB needed);
  // k_onehot overwrites it as the final kernel.
  float* sums = out_v;

  // partitionable (fold-like) split of key(42) into 5 subkeys
  uint32_t keys[5][2];
  for (int i = 0; i < 5; ++i) {
    TFOut r = tf2x32(0u, 42u, 0u, (uint32_t)i);
    keys[i][0] = r.a; keys[i][1] = r.b;
  }

  hipLaunchKernelGGL(k_wt,  dim3(2560),  dim3(256), 0, stream, W, Wt);
  hipLaunchKernelGGL(k_idx, dim3(32768), dim3(256), 0, stream, v0, idx);

  // h0 = sample_h(keys[0], v0) -> h_given_v0 output + mask
  hipLaunchKernelGGL(k_sample_h, dim3(B_DIM / 16 * 2), dim3(256), 0, stream,
                     Wt, c1, idx, out_h0, mask, keys[0][0], keys[0][1]);
  // iter 0: v = sample_v(keys[1], h0); h1 = sample_h(keys[2], v)
  hipLaunchKernelGGL(k_gemm_v, dim3(B_DIM / 16), dim3(256), 0, stream,
                     W, mask, sums);
  hipLaunchKernelGGL(k_gumbel_v, dim3(B_DIM * 128 / 256), dim3(256), 0, stream,
                     sums, b2, idx, keys[1][0], keys[1][1]);
  hipLaunchKernelGGL(k_sample_h, dim3(B_DIM / 16 * 2), dim3(256), 0, stream,
                     Wt, c1, idx, (float*)nullptr, mask, keys[2][0], keys[2][1]);
  // iter 1: v = sample_v(keys[3], h1); h2 = sample_h(keys[4], v)
  hipLaunchKernelGGL(k_gemm_v, dim3(B_DIM / 16), dim3(256), 0, stream,
                     W, mask, sums);
  hipLaunchKernelGGL(k_gumbel_v, dim3(B_DIM * 128 / 256), dim3(256), 0, stream,
                     sums, b2, idx, keys[3][0], keys[3][1]);
  hipLaunchKernelGGL(k_sample_h, dim3(B_DIM / 16 * 2), dim3(256), 0, stream,
                     Wt, c1, idx, out_h, mask, keys[4][0], keys[4][1]);
  // final v one-hot output
  hipLaunchKernelGGL(k_onehot, dim3(163840), dim3(256), 0, stream, idx, out_v);
}

// Round 3
// 2241.898 us; speedup vs baseline: 1.9632x; 1.9632x over previous
//
#include <hip/hip_runtime.h>
#include <cstdint>
#include <cstddef>

// =====================================================================
// RBM Gibbs sampling, bit-exact replication of JAX-on-CPU reference.
// ROUND 13 (perf):
// (1) k_sample_h rewritten DENSE (R12's list-walk chunked scheme was
//     barrier/imbalance-bound: 31% VALU, 1103us). Same trick as the
//     validated k_gemm_v: total[b][h] = sum_{k asc} Wt[k][h]*f[b][k],
//     f = (idx[b][k&511] == k>>9) in {0,1}, slab folds at k%320==0
//     (8 tiles of 320 = exact KC alignment; phantom slab-8 fold was a
//     +0.0 identity). fma with f=0 adds +/-0.0 to a never--0.0 psum
//     => bit-identical to the selected-k sequential chain. Bit-floats
//     expanded per-tile into LDS tbf[320][16] (broadcast reads),
//     16 b's per block share every Wt row: L2 8.6GB -> 2.7GB.
// (2) v_pk_fma_f32 packing in BOTH GEMMs: 16 b-accumulators held as
//     8 f32x2 pairs (independent per-half chains, IEEE-identical;
//     PKFMA validated in R11). Halves VALU issue. gemm_v: 2 splats +
//     16 pk_fma per h (was 32 fma); sample_h: 1 splat + 8 pk per k.
// Semantics FROZEN (rounds 6-12 passed, absmax=0):
//  - threefry2x32 partitionable; fold-like split; seed(42)->(0,42).
//  - cephes-Horner exp, Pommier-Horner log (q1/q2 tail), no contract.
//  - sigmoid = 1/(1+exp(-x)) IEEE div; gumbel tiny-clamp; first-max
//    argmax; bernoulli u<p; v-GEMM K=256 single sequential chain.
//  - h-GEMM: Eigen gebp kc=320 slab fold, k ascending (c-major).
// ws layout unchanged; sums scratch in out_v region (167.77MB exact);
// sentinel reads back ws_size as absmax if short.
// =====================================================================

#define B_DIM 16384
#define C_DIM 5
#define H_DIM 256
#define V_DIM 512

struct TFOut { uint32_t a, b; };

typedef float f32x2 __attribute__((ext_vector_type(2)));
typedef float f32x4 __attribute__((ext_vector_type(4)));

#if __has_builtin(__builtin_elementwise_fma)
#define PKFMA(A, B, C) __builtin_elementwise_fma((A), (B), (C))
#else
static __device__ inline f32x2 pkfma_(f32x2 a, f32x2 b, f32x2 c) {
  f32x2 r; r.x = fmaf(a.x, b.x, c.x); r.y = fmaf(a.y, b.y, c.y); return r;
}
#define PKFMA(A, B, C) pkfma_((A), (B), (C))
#endif

__host__ __device__ static inline TFOut tf2x32(uint32_t k0, uint32_t k1,
                                               uint32_t c0, uint32_t c1) {
  uint32_t ks2 = k0 ^ k1 ^ 0x1BD11BDAu;
  uint32_t x0 = c0 + k0, x1 = c1 + k1;
#define TF_R(r) { x0 += x1; x1 = (x1 << r) | (x1 >> (32 - r)); x1 ^= x0; }
  TF_R(13) TF_R(15) TF_R(26) TF_R(6)
  x0 += k1;  x1 += ks2 + 1u;
  TF_R(17) TF_R(29) TF_R(16) TF_R(24)
  x0 += ks2; x1 += k0 + 2u;
  TF_R(13) TF_R(15) TF_R(26) TF_R(6)
  x0 += k0;  x1 += k1 + 3u;
  TF_R(17) TF_R(29) TF_R(16) TF_R(24)
  x0 += k1;  x1 += ks2 + 4u;
  TF_R(13) TF_R(15) TF_R(26) TF_R(6)
  x0 += ks2; x1 += k0 + 5u;
#undef TF_R
  TFOut o; o.a = x0; o.b = x1; return o;
}

// partitionable random_bits, 32-bit width, element index i (< 2^32)
__device__ static inline uint32_t rng_bits(uint32_t k0, uint32_t k1, uint32_t i) {
  TFOut r = tf2x32(k0, k1, 0u, i);
  return r.a ^ r.b;
}

__device__ static inline float bits_to_unit_float(uint32_t bits) {
  return __uint_as_float((bits >> 9) | 0x3F800000u) - 1.0f;
}

// XLA GenerateVF32Exp replica (cephes Horner port), mul+add separate,
// NO contraction.
__device__ static float xla_exp(float x_in) {
#pragma clang fp contract(off)
  float x = fminf(x_in, 88.3762626647950f);
  x = fmaxf(x, -88.3762626647949f);
  float fx = floorf(x * 1.44269504088896341f + 0.5f);
  float tmp = fx * 0.693359375f;
  float z = fx * -2.12194440e-4f;
  x = x - tmp;
  x = x - z;
  z = x * x;
  float y = 1.9875691500e-4f;
  y = y * x + 1.3981999507e-3f;
  y = y * x + 8.3334519073e-3f;
  y = y * x + 4.1665795894e-2f;
  y = y * x + 1.6666665459e-1f;
  y = y * x + 5.0000001201e-1f;
  y = y * z + x;
  y = y + 1.0f;
  int n = (int)fx;
  y = y * __uint_as_float((uint32_t)(n + 127) << 23);
  return y;
}

// XLA GenerateVF32Log replica = Pommier/Eigen3.3 log_ps (Horner + tail:
// y+=e*q1; y-=0.5*z; x+=y; x+=e*q2). NO contraction.
__device__ static float xla_log(float x_in) {
#pragma clang fp contract(off)
  float xv = fmaxf(x_in, 1.17549435e-38f);      // min_norm_pos clamp
  uint32_t bits = __float_as_uint(xv);
  float e = (float)((int)(bits >> 23) - 126);
  float x = __uint_as_float((bits & 0x007FFFFFu) | 0x3F000000u);  // [0.5,1)
  bool m = (x < 0.707106781186547524f);
  float tmp = m ? x : 0.0f;
  x = x - 1.0f;
  e = e - (m ? 1.0f : 0.0f);
  x = x + tmp;
  float z = x * x;
  float y = 7.0376836292e-2f;
  y = y * x + -1.1514610310e-1f;
  y = y * x + 1.1676998740e-1f;
  y = y * x + -1.2420140846e-1f;
  y = y * x + 1.4249322787e-1f;
  y = y * x + -1.6668057665e-1f;
  y = y * x + 2.0000714765e-1f;
  y = y * x + -2.4999993993e-1f;
  y = y * x + 3.3333331174e-1f;
  y = y * x;
  y = y * z;
  float t1 = e * -2.12194440e-4f;
  y = y + t1;
  float t2 = z * 0.5f;
  y = y - t2;
  x = x + y;
  float t3 = e * 0.693359375f;
  x = x + t3;
  return x;
}

// ---------------- kernels ----------------

__global__ void k_sentinel(float* out, float d) {
  out[0] = d;
}

// v0 one-hot (B,C,V) -> idx (B,V) u8
__global__ __launch_bounds__(256) void k_idx(const float* __restrict__ v0,
                                             uint8_t* __restrict__ idx) {
  int t = blockIdx.x * 256 + threadIdx.x;          // b*V + v
  int b = t >> 9, v = t & 511;
  const float* p = v0 + (size_t)b * (C_DIM * V_DIM) + v;
  int cf = 0;
#pragma unroll
  for (int c = 0; c < C_DIM; ++c)
    if (p[c * V_DIM] > 0.5f) cf = c;
  idx[t] = (uint8_t)cf;
}

// W (c,h,v) -> Wt (c,v,h)
__global__ __launch_bounds__(256) void k_wt(const float* __restrict__ W,
                                            float* __restrict__ Wt) {
  int t = blockIdx.x * 256 + threadIdx.x;          // (c, v, h)
  int h = t & 255; int rest = t >> 8; int v = rest & 511; int c = rest >> 9;
  Wt[t] = W[((size_t)c * H_DIM + h) * V_DIM + v];
}

// =====================================================================
// k_sample_h (DENSE): total[b][h] = sum_{k=0..2559 asc} Wt[k][h]*f[b][k]
// with psum reset at k%320==0 (8 exact slabs).  Block = 16 b x 256 h
// (thread owns h=t; 16 b's as 8 f32x2 pk pairs).  Per k: 1 dword W load
// + splat + 4 broadcast ds_read_b128 + 8 pk_fma.
// =====================================================================
#define SH_K(u)                                                        \
  {                                                                    \
    f32x2 ww = {w8[u], w8[u]};                                         \
    const f32x4* fp_ = (const f32x4*)&tbf[kk + u][0];                  \
    f32x4 qA = fp_[0], qB = fp_[1], qC = fp_[2], qD = fp_[3];          \
    ps[0] = PKFMA(ww, __builtin_shufflevector(qA, qA, 0, 1), ps[0]);   \
    ps[1] = PKFMA(ww, __builtin_shufflevector(qA, qA, 2, 3), ps[1]);   \
    ps[2] = PKFMA(ww, __builtin_shufflevector(qB, qB, 0, 1), ps[2]);   \
    ps[3] = PKFMA(ww, __builtin_shufflevector(qB, qB, 2, 3), ps[3]);   \
    ps[4] = PKFMA(ww, __builtin_shufflevector(qC, qC, 0, 1), ps[4]);   \
    ps[5] = PKFMA(ww, __builtin_shufflevector(qC, qC, 2, 3), ps[5]);   \
    ps[6] = PKFMA(ww, __builtin_shufflevector(qD, qD, 0, 1), ps[6]);   \
    ps[7] = PKFMA(ww, __builtin_shufflevector(qD, qD, 2, 3), ps[7]);   \
  }

__global__ __launch_bounds__(256, 4) void k_sample_h(
    const float* __restrict__ Wt, const float* __restrict__ c1g,
    const uint8_t* __restrict__ idx,
    float* __restrict__ out_h, uint32_t* __restrict__ out_mask,
    uint32_t key0, uint32_t key1) {
  __shared__ uint8_t  sidx[16][V_DIM];                 // b-major (coalesced in)
  __shared__ uint8_t  sidxT[V_DIM][16];                // v-major (for expand)
  __shared__ __align__(16) float tbf[320][16];         // f-bits of one slab
  int t = threadIdx.x;
  int b0 = blockIdx.x * 16;
  int wv = t >> 6, lane = t & 63;
  int h = t;

  // stage idx rows for the 16 b's (flat, coalesced)
  {
    const uint32_t* src = (const uint32_t*)(idx + (size_t)b0 * V_DIM);
    uint32_t* dst = (uint32_t*)&sidx[0][0];
    for (int i = t; i < 2048; i += 256) dst[i] = src[i];
  }
  __syncthreads();
  // transpose to v-major (one-time; conflicts negligible)
  {
    int bi = t >> 4, vb = (t & 15) * 32;
#pragma unroll
    for (int q = 0; q < 32; ++q)
      sidxT[vb + q][bi] = sidx[bi][vb + q];
  }
  __syncthreads();

  f32x2 ps[8], tt[8];
#pragma unroll
  for (int j = 0; j < 8; ++j) {
    ps[j] = (f32x2){0.f, 0.f};
    tt[j] = (f32x2){0.f, 0.f};
  }

  const float* wcol = Wt + h;    // Wt[k][h], k stride = H_DIM floats

  for (int tile = 0; tile < 8; ++tile) {
    int kbase = tile * 320;
    // ---- expand f-bits for this slab: tbf[kk][bi] ----
    {
      int bi = t & 15, kr = t >> 4;
#pragma unroll
      for (int g = 0; g < 20; ++g) {
        int kk = kr + (g << 4);
        int k = kbase + kk;
        int cc = k >> 9, v = k & 511;
        tbf[kk][bi] = (sidxT[v][bi] == (uint8_t)cc) ? 1.0f : 0.0f;
      }
    }
    __syncthreads();
    // ---- slab fold at k%320==0 (identity at tile 0) ----
#pragma unroll
    for (int j = 0; j < 8; ++j) {
      tt[j] += ps[j];
      ps[j] = (f32x2){0.f, 0.f};
    }
    // ---- dense accumulate over the slab, k ascending ----
    for (int kk = 0; kk < 320; kk += 8) {
      float w8[8];
#pragma unroll
      for (int u = 0; u < 8; ++u)
        w8[u] = wcol[(size_t)(kbase + kk + u) * H_DIM];
      SH_K(0) SH_K(1) SH_K(2) SH_K(3)
      SH_K(4) SH_K(5) SH_K(6) SH_K(7)
    }
    __syncthreads();       // reads done before next tile's expand
  }
#pragma unroll
  for (int j = 0; j < 8; ++j) tt[j] += ps[j];   // final slab fold

  // ---- epilogue: sigmoid + bernoulli + out_h + mask ----
  float c1h = c1g[h];
#pragma unroll
  for (int j = 0; j < 8; ++j) {
#pragma unroll
    for (int e = 0; e < 2; ++e) {
      int b = b0 + 2 * j + e;
      float total = (e == 0 ? tt[j].x : tt[j].y) + c1h;
      float p = 1.0f / (1.0f + xla_exp(-total));   // IEEE div, logistic form
      float u = bits_to_unit_float(
          rng_bits(key0, key1, (uint32_t)(b * H_DIM + h)));
      bool hbit = (u < p);
      if (out_h) out_h[(size_t)b * H_DIM + h] = hbit ? 1.0f : 0.0f;
      unsigned long long m = __ballot(hbit);
      if (lane == 0) {
        out_mask[(size_t)b * 8 + wv * 2 + 0] = (uint32_t)(m & 0xFFFFFFFFull);
        out_mask[(size_t)b * 8 + wv * 2 + 1] = (uint32_t)(m >> 32);
      }
    }
  }
}

// =====================================================================
// k_gemm_v: sums[c][b][v] = h-ascending dense fma chain (f in {0,1}).
// Block = 16 b x 512 v; thread = 16 b (8 pk pairs) x 2 v.  Per h:
// 1 float2 W load + 2 splats + 4 broadcast ds_read_b128 + 16 pk_fma.
// Chain per (b,v) identical to R11/R12 (bit-exact).
// =====================================================================
#define GV_H(u)                                                        \
  {                                                                    \
    f32x2 ww0 = {w4[u].x, w4[u].x};                                    \
    f32x2 ww1 = {w4[u].y, w4[u].y};                                    \
    const f32x4* fp_ = (const f32x4*)&tbf[hh + u][0];                  \
    f32x4 qA = fp_[0], qB = fp_[1], qC = fp_[2], qD = fp_[3];          \
    f32x2 f0 = __builtin_shufflevector(qA, qA, 0, 1);                  \
    f32x2 f1 = __builtin_shufflevector(qA, qA, 2, 3);                  \
    f32x2 f2 = __builtin_shufflevector(qB, qB, 0, 1);                  \
    f32x2 f3 = __builtin_shufflevector(qB, qB, 2, 3);                  \
    f32x2 f4 = __builtin_shufflevector(qC, qC, 0, 1);                  \
    f32x2 f5 = __builtin_shufflevector(qC, qC, 2, 3);                  \
    f32x2 f6 = __builtin_shufflevector(qD, qD, 0, 1);                  \
    f32x2 f7 = __builtin_shufflevector(qD, qD, 2, 3);                  \
    av0[0] = PKFMA(ww0, f0, av0[0]); av1[0] = PKFMA(ww1, f0, av1[0]);  \
    av0[1] = PKFMA(ww0, f1, av0[1]); av1[1] = PKFMA(ww1, f1, av1[1]);  \
    av0[2] = PKFMA(ww0, f2, av0[2]); av1[2] = PKFMA(ww1, f2, av1[2]);  \
    av0[3] = PKFMA(ww0, f3, av0[3]); av1[3] = PKFMA(ww1, f3, av1[3]);  \
    av0[4] = PKFMA(ww0, f4, av0[4]); av1[4] = PKFMA(ww1, f4, av1[4]);  \
    av0[5] = PKFMA(ww0, f5, av0[5]); av1[5] = PKFMA(ww1, f5, av1[5]);  \
    av0[6] = PKFMA(ww0, f6, av0[6]); av1[6] = PKFMA(ww1, f6, av1[6]);  \
    av0[7] = PKFMA(ww0, f7, av0[7]); av1[7] = PKFMA(ww1, f7, av1[7]);  \
  }

__global__ __launch_bounds__(256, 4) void k_gemm_v(
    const float* __restrict__ W, const uint32_t* __restrict__ mask,
    float* __restrict__ sums) {
  __shared__ uint32_t smask[16][8];
  __shared__ __align__(16) float tbf[H_DIM][16];
  int t = threadIdx.x;
  int b0 = blockIdx.x * 16;
  if (t < 128) smask[t >> 3][t & 7] = mask[(size_t)b0 * 8 + t];
  __syncthreads();
  {
    int h = t;
    uint32_t w = (uint32_t)(h >> 5), s = (uint32_t)(h & 31), x = 0;
#pragma unroll
    for (int j = 0; j < 16; ++j)
      x |= ((smask[j][w] >> s) & 1u) << j;
#pragma unroll
    for (int i = 0; i < 16; ++i)
      tbf[h][i] = (float)((x >> i) & 1u);
  }
  __syncthreads();

  int wv = t >> 6, lane = t & 63;
  int v0 = wv * 128 + (lane << 1);

  for (int c = 0; c < C_DIM; ++c) {
    f32x2 av0[8], av1[8];
#pragma unroll
    for (int j = 0; j < 8; ++j) {
      av0[j] = (f32x2){0.f, 0.f};
      av1[j] = (f32x2){0.f, 0.f};
    }
    const float* wp = W + (size_t)c * (H_DIM * V_DIM) + v0;
    for (int hh = 0; hh < H_DIM; hh += 4) {
      float2 w4[4];
#pragma unroll
      for (int u = 0; u < 4; ++u)
        w4[u] = *(const float2*)(wp + (size_t)(hh + u) * V_DIM);
      GV_H(0) GV_H(1) GV_H(2) GV_H(3)
    }
#pragma unroll
    for (int j = 0; j < 8; ++j) {
      float2 oA; oA.x = av0[j].x; oA.y = av1[j].x;    // b = b0+2j
      *(float2*)&sums[((size_t)c * B_DIM + b0 + 2 * j) * V_DIM + v0] = oA;
      float2 oB; oB.x = av0[j].y; oB.y = av1[j].y;    // b = b0+2j+1
      *(float2*)&sums[((size_t)c * B_DIM + b0 + 2 * j + 1) * V_DIM + v0] = oB;
    }
  }
}

// =====================================================================
// k_gumbel_v: v = categorical over c (gumbel + first-max argmax),
// reading the staged sums. Expressions/RNG identical to R11 epilogue.
// =====================================================================
__global__ __launch_bounds__(256, 4) void k_gumbel_v(
    const float* __restrict__ sums, const float* __restrict__ b2,
    uint8_t* __restrict__ idx_out, uint32_t key0, uint32_t key1) {
  int gidx = blockIdx.x * 256 + threadIdx.x;
  int b = gidx >> 7;
  int v0 = (gidx & 127) << 2;
  float best[4];
  uint32_t bc = 0;
#pragma unroll
  for (int c = 0; c < C_DIM; ++c) {
    float4 av = *(const float4*)&sums[((size_t)c * B_DIM + b) * V_DIM + v0];
    float4 bv = *(const float4*)&b2[c * V_DIM + v0];
    uint32_t ib = ((uint32_t)b * C_DIM + (uint32_t)c) * V_DIM + (uint32_t)v0;
    float avq[4] = {av.x, av.y, av.z, av.w};
    float bvq[4] = {bv.x, bv.y, bv.z, bv.w};
#pragma unroll
    for (int q = 0; q < 4; ++q) {
      float uf = bits_to_unit_float(rng_bits(key0, key1, ib + (uint32_t)q));
      if (uf == 0.0f) uf = 1.17549435e-38f;        // u + tiny semantics
      float gz = -xla_log(-xla_log(uf));
      float z = gz + (avq[q] + bvq[q]);
      if (c == 0 || z > best[q]) {
        best[q] = z;
        bc = (bc & ~(0xFFu << (8 * q))) | ((uint32_t)c << (8 * q));
      }
    }
  }
  *(uint32_t*)(idx_out + (size_t)b * V_DIM + v0) = bc;
}

// idx -> one-hot f32 (B,C,V)
__global__ __launch_bounds__(256) void k_onehot(const uint8_t* __restrict__ idx,
                                                float* __restrict__ out) {
  int t = blockIdx.x * 256 + threadIdx.x;     // b*C*V + c*V + v
  int v = t & 511; int rest = t >> 9; int c = rest % C_DIM; int b = rest / C_DIM;
  out[t] = (idx[(size_t)b * V_DIM + v] == c) ? 1.0f : 0.0f;
}

// ---------------- launch ----------------

extern "C" void kernel_launch(void* const* d_in, const int* in_sizes, int n_in,
                              void* d_out, int out_size, void* d_ws, size_t ws_size,
                              hipStream_t stream) {
  float* out = (float*)d_out;

  // ---- structural sentinels ----
  const size_t WS_NEED = 2621440ull      // Wt
                       + 2621440ull      // (reserved, layout kept)
                       + 8388608ull      // idx
                       + 524288ull;      // mask  = 14,155,776 B
  float D = 0.0f;
  if (n_in < 4)                       D = 910.0f + (float)n_in;
  else if (in_sizes[0] != 41943040)   D = 920.0f;
  else if (in_sizes[1] != 655360)     D = 921.0f;
  else if (in_sizes[2] != 2560)       D = 922.0f;
  else if (in_sizes[3] != 256)        D = 923.0f;
  else if (out_size != 50331648)      D = 930.0f + (float)out_size * 1e-6f;
  else if (ws_size < WS_NEED)         D = 100.0f + (float)(ws_size >> 20);
  if (D != 0.0f) {
    hipLaunchKernelGGL(k_sentinel, dim3(1), dim3(1), 0, stream, out, D);
    return;
  }

  const float* v0 = (const float*)d_in[0];
  const float* W  = (const float*)d_in[1];
  const float* b2 = (const float*)d_in[2];   // (C,V)
  const float* c1 = (const float*)d_in[3];   // (H)

  float* out_v  = out;                                         // B*C*V
  float* out_h  = out + (size_t)B_DIM * C_DIM * V_DIM;         // B*H (final h)
  float* out_h0 = out_h + (size_t)B_DIM * H_DIM;               // B*H (h|v0)

  char* ws = (char*)d_ws;
  float*    Wt   = (float*)(ws);                    // 2,621,440 B
  uint8_t*  idx  = (uint8_t*)(ws + 5242880);        // 8,388,608 B
  uint32_t* mask = (uint32_t*)(ws + 13631488);      //   524,288 B

  // sums scratch lives in the out_v region (167.77MB, exact fit);
  // k_onehot overwrites it as the final kernel.
  float* sums = out_v;

  // partitionable (fold-like) split of key(42) into 5 subkeys
  uint32_t keys[5][2];
  for (int i = 0; i < 5; ++i) {
    TFOut r = tf2x32(0u, 42u, 0u, (uint32_t)i);
    keys[i][0] = r.a; keys[i][1] = r.b;
  }

  hipLaunchKernelGGL(k_wt,  dim3(2560),  dim3(256), 0, stream, W, Wt);
  hipLaunchKernelGGL(k_idx, dim3(32768), dim3(256), 0, stream, v0, idx);

  // h0 = sample_h(keys[0], v0) -> h_given_v0 output + mask
  hipLaunchKernelGGL(k_sample_h, dim3(B_DIM / 16), dim3(256), 0, stream,
                     Wt, c1, idx, out_h0, mask, keys[0][0], keys[0][1]);
  // iter 0: v = sample_v(keys[1], h0); h1 = sample_h(keys[2], v)
  hipLaunchKernelGGL(k_gemm_v, dim3(B_DIM / 16), dim3(256), 0, stream,
                     W, mask, sums);
  hipLaunchKernelGGL(k_gumbel_v, dim3(B_DIM * 128 / 256), dim3(256), 0, stream,
                     sums, b2, idx, keys[1][0], keys[1][1]);
  hipLaunchKernelGGL(k_sample_h, dim3(B_DIM / 16), dim3(256), 0, stream,
                     Wt, c1, idx, (float*)nullptr, mask, keys[2][0], keys[2][1]);
  // iter 1: v = sample_v(keys[3], h1); h2 = sample_h(keys[4], v)
  hipLaunchKernelGGL(k_gemm_v, dim3(B_DIM / 16), dim3(256), 0, stream,
                     W, mask, sums);
  hipLaunchKernelGGL(k_gumbel_v, dim3(B_DIM * 128 / 256), dim3(256), 0, stream,
                     sums, b2, idx, keys[3][0], keys[3][1]);
  hipLaunchKernelGGL(k_sample_h, dim3(B_DIM / 16), dim3(256), 0, stream,
                     Wt, c1, idx, out_h, mask, keys[4][0], keys[4][1]);
  // final v one-hot output
  hipLaunchKernelGGL(k_onehot, dim3(163840), dim3(256), 0, stream, idx, out_v);
}